// Round 24
// baseline (93.036 us; speedup 1.0000x reference)
//
#include <hip/hip_runtime.h>
#include <hip/hip_fp16.h>

typedef __attribute__((ext_vector_type(8))) _Float16 half8;
typedef __attribute__((ext_vector_type(2))) __fp16 fp16x2;
typedef __attribute__((ext_vector_type(4))) float f32x4;
typedef unsigned short u16;
typedef unsigned int u32;

__device__ __forceinline__ u16 f2h(float f) {
  union { _Float16 h; u16 u; } cv; cv.h = (_Float16)f; return cv.u;
}

__device__ __forceinline__ u32 pkrtz(float a, float b) {
  union { fp16x2 h; u32 u; } cv;
  cv.h = __builtin_amdgcn_cvt_pkrtz(a, b);
  return cv.u;
}

__device__ __forceinline__ f32x4 mfma16h(half8 a, half8 b, f32x4 c) {
  return __builtin_amdgcn_mfma_f32_16x16x32_f16(a, b, c, 0, 0, 0);
}

__device__ __forceinline__ void gload_lds16(const void* g, void* l) {
  __builtin_amdgcn_global_load_lds(
      (const __attribute__((address_space(1))) void*)g,
      (__attribute__((address_space(3))) void*)l, 16, 0, 0);
}

__device__ __forceinline__ half8 ldh8(const char* p) {
  union { half8 h; int4 v; } r; r.v = *(const int4*)p; return r.h;
}

// 8-wide fp16 product via v_pk_mul_f16
__device__ __forceinline__ uint4 pkmul4(uint4 x, uint4 y) {
  union U { uint4 v; __half2 h[4]; };
  U X, Y, E; X.v = x; Y.v = y;
  #pragma unroll
  for (int i = 0; i < 4; i++) E.h[i] = __hmul2(X.h[i], Y.h[i]);
  return E.v;
}
__device__ __forceinline__ half8 as_h8(uint4 v) {
  union { uint4 v; half8 h; } r; r.v = v; return r.h;
}

// ---- one row of weight-norm (fp16 out), wave-cooperative ----
__device__ __forceinline__ void wn_row(const float* __restrict__ v,
                                       const float* __restrict__ g,
                                       int K, int Nreal, u16* __restrict__ outW,
                                       int row, int l) {
  if (row >= Nreal) {
    for (int k = l; k < K; k += 64) outW[row * K + k] = 0;
    return;
  }
  const float* vr = v + (size_t)row * K;
  float ss = 0.f;
  for (int k = l * 4; k < K; k += 256) {
    f32x4 x = *(const f32x4*)(vr + k);
    ss += x.x * x.x + x.y * x.y + x.z * x.z + x.w * x.w;
  }
  #pragma unroll
  for (int m = 32; m >= 1; m >>= 1) ss += __shfl_xor(ss, m, 64);
  const float scale = g[row] / sqrtf(ss);
  for (int k = l; k < K; k += 64) outW[row * K + k] = f2h(vr[k] * scale);
}

// ================= merged prep: cvt (0..4671) + weight-norm (4672..4995) +
// pos scatter / ij_tab (4996..5631), one launch =================
// ij_tab now 768 entries (pads [630,768) -> 35*36+35) for the 256-row edge blocks.
__global__ __launch_bounds__(256) void prep(
    const float* __restrict__ node, u16* __restrict__ node_h,
    const float* __restrict__ qf, u16* __restrict__ q_h,
    const float* __restrict__ v_obj, const float* __restrict__ g_obj,
    const float* __restrict__ v_q,   const float* __restrict__ g_q,
    const float* __restrict__ v_l1,  const float* __restrict__ g_l1,
    const float* __restrict__ v_l2,  const float* __restrict__ g_l2,
    u16* __restrict__ Wobjh, u16* __restrict__ Wqh,
    u16* __restrict__ W1f,   u16* __restrict__ W2p,
    const int* __restrict__ indexes, int* __restrict__ posPair,
    int* __restrict__ ij_tab) {
  const int b = blockIdx.x;
  if (b < 4672) {
    const int i = (b * 256 + threadIdx.x) * 8;
    const float* in; u16* out; int off;
    if (i < 9437184) { in = node; out = node_h; off = i; }
    else             { in = qf;   out = q_h;    off = i - 9437184; }
    f32x4 a = *(const f32x4*)(in + off);
    f32x4 c = *(const f32x4*)(in + off + 4);
    uint4 r;
    r.x = pkrtz(a.x, a.y); r.y = pkrtz(a.z, a.w);
    r.z = pkrtz(c.x, c.y); r.w = pkrtz(c.z, c.w);
    *(uint4*)(out + off) = r;
    return;
  }
  const int sub = threadIdx.x >> 6, l = threadIdx.x & 63;
  const int b2 = b - 4672;
  if (b2 < 128) {
    wn_row(v_obj, g_obj, 2048, 512, Wobjh, b2 * 4 + sub, l);
  } else if (b2 < 256) {
    wn_row(v_q, g_q, 1024, 512, Wqh, (b2 - 128) * 4 + sub, l);
  } else if (b2 < 320) {
    const int row = (b2 - 256) * 4 + sub;
    const float* vr = v_l1 + (size_t)row * 512;
    float ss = 0.f;
    for (int k = l * 4; k < 512; k += 256) {
      f32x4 x = *(const f32x4*)(vr + k);
      ss += x.x * x.x + x.y * x.y + x.z * x.z + x.w * x.w;
    }
    #pragma unroll
    for (int m = 32; m >= 1; m >>= 1) ss += __shfl_xor(ss, m, 64);
    const float scale = g_l1[row] / sqrtf(ss);
    const int swz = (row >> 1) & 3;
    for (int c = l; c < 512; c += 64) {
      const int kc = c >> 5, col = c & 31, q = col >> 3, e = col & 7;
      W1f[kc * 8192 + row * 32 + ((q ^ swz) << 3) + e] = f2h(vr[c] * scale);
    }
  } else if (b2 < 324) {
    wn_row(v_l2, g_l2, 256, 8, W2p, (b2 - 320) * 4 + sub, l);
  } else {
    const int m = (b2 - 324) * 256 + threadIdx.x;
    if (m < 161280) {
      const int idx = indexes[m];
      const int bi = idx / 1296;
      const int rem = idx - bi * 1296;
      const int i = rem / 36, j = rem - i * 36;
      const int i2 = (i < j) ? i : j, j2 = (i < j) ? j : i;
      const int p = i2 * (71 - i2) / 2 + (j2 - i2 - 1);
      posPair[(bi * 640 + p) * 2 + ((i < j) ? 0 : 1)] = m;
    } else {
      const int u = m - 161280;
      if (u < 1296) {
        const int i = u / 36, j = u - i * 36;
        if (i < j) ij_tab[i * (71 - i) / 2 + (j - i - 1)] = u;
      } else if (u < 1434) {
        ij_tab[630 + (u - 1296)] = 35 * 36 + 35;
      }
    }
  }
}

// ================= stage-1 GEMM, 128x32 N-tiles (R21-proven) =================
__global__ __launch_bounds__(256, 3) void gemm_n32(
    const u16* __restrict__ node_h, const u16* __restrict__ Wobjh,
    const float* __restrict__ b_obj, u16* __restrict__ A2h,
    const u16* __restrict__ q_h, const u16* __restrict__ Wqh,
    const float* __restrict__ b_q, u16* __restrict__ qp_h) {
  __shared__ char smem[2][20480];   // [buf][ A 128x128B | B 32x128B ]
  const int t = threadIdx.x, l = t & 63, w = t >> 6;
  const int lr = l & 15, lg = l >> 4;
  const int wm = w & 1, wn2 = w >> 1;

  const bool isq = (blockIdx.x == 36);
  const u16* Ab = isq ? q_h : node_h;
  const u16* Wb = isq ? Wqh : Wobjh;
  const float* bias = isq ? b_q : b_obj;
  u16* outp = isq ? qp_h : A2h;
  const int K = isq ? 1024 : 2048;
  const int nstep = isq ? 16 : 32;
  const int bm = isq ? 0 : blockIdx.x * 128;
  const int bn = blockIdx.y * 32;
  const int ldb = K * 2;

  const char* Abase = (const char*)(Ab + (size_t)bm * K);
  const char* Bbase = (const char*)(Wb + (size_t)bn * K);

  auto stage = [&](int buf, int ks) {
    const char* asrc = Abase + ks * 128;
    const char* bsrc = Bbase + ks * 128;
    #pragma unroll
    for (int it = 0; it < 4; it++) {
      const int c = it * 256 + w * 64 + l;
      const int row = c >> 3;
      const int cb = ((c & 7) * 16) ^ ((row & 7) << 4);
      gload_lds16(asrc + (size_t)row * ldb + cb, &smem[buf][(it * 256 + w * 64) * 16]);
    }
    {
      const int c = w * 64 + l;
      const int row = c >> 3;
      const int cb = ((c & 7) * 16) ^ ((row & 7) << 4);
      gload_lds16(bsrc + (size_t)row * ldb + cb,
                  &smem[buf][16384 + (w * 64) * 16]);
    }
  };

  stage(0, 0);
  asm volatile("s_waitcnt vmcnt(0)" ::: "memory");
  __builtin_amdgcn_s_barrier();

  f32x4 acc[4] = {};
  f32x4 acc2[4] = {};
  for (int ks = 0; ks < nstep; ks++) {
    const int cur = ks & 1;
    if (ks + 1 < nstep) stage(cur ^ 1, ks + 1);
    const char* As = smem[cur];
    const char* Bs = smem[cur] + 16384;
    #pragma unroll
    for (int kk = 0; kk < 2; kk++) {
      const int kswz = (kk * 64 + lg * 16) ^ ((lr & 7) << 4);
      half8 af[4], bf;
      #pragma unroll
      for (int m = 0; m < 4; m++)
        af[m] = ldh8(As + (wm * 64 + m * 16 + lr) * 128 + kswz);
      bf = ldh8(Bs + (wn2 * 16 + lr) * 128 + kswz);
      acc[0] = mfma16h(af[0], bf, acc[0]);
      acc[1] = mfma16h(af[1], bf, acc[1]);
      acc2[0] = mfma16h(af[2], bf, acc2[0]);
      acc2[1] = mfma16h(af[3], bf, acc2[1]);
    }
    asm volatile("s_waitcnt vmcnt(0)" ::: "memory");
    __builtin_amdgcn_s_barrier();
  }

  const int c = bn + wn2 * 16 + lr;
  const float bv = bias[c];
  #pragma unroll
  for (int m = 0; m < 4; m++) {
    const f32x4 a = (m < 2) ? acc[m] : acc2[m - 2];
    #pragma unroll
    for (int q = 0; q < 4; q++) {
      const int r = bm + wm * 64 + m * 16 + lg * 4 + q;
      outp[(size_t)r * 512 + c] = f2h(a[q] + bv);
    }
  }
}

// ================= fused edge kernel v14: M=256, 512 threads (8 waves 4Mx2N) =================
// Per-wave inner loop IDENTICAL to v11 (17 LDS reads : 32 MFMA, acc[4][8],
// same swizzles); only the wave->tile map scales. waves/CU 8 -> 16 at
// 2 blocks/CU; W1 DMA per pair halves. Grid (3,128); pads p>=630 masked.
// LDS: nf 36x1040 | qp 1KB | W1 dbuf 2x16KB = 71,232 B. Epilogue: two
// 128-row phases, h-tile [128][528B] = 67,584 B aliases tables/W1.
#define OFF_QP 37440
#define OFF_W1 38464
#define EDGE_SMEM 71232

__global__ __launch_bounds__(512, 2) void edge_v14(
    const u16* __restrict__ NFg, const u16* __restrict__ QPg,
    const u16* __restrict__ W1f, const float* __restrict__ b1,
    const u16* __restrict__ W2p, const float* __restrict__ b2,
    const int* __restrict__ posPair, const int* __restrict__ ij_tab,
    float* __restrict__ out) {
  extern __shared__ char smem[];
  const int t = threadIdx.x, l = t & 63, w = t >> 6;
  const int lr = l & 15, lg = l >> 4;
  const int wm = w & 3, wn = w >> 2;
  const int bi = blockIdx.y;
  const int mb = blockIdx.x * 256;

  // ---- prologue: nf rows 0..35 + qp row + W1 chunk 0 ----
  #pragma unroll
  for (int it = 0; it < 5; it++) {
    const int row = it * 8 + w;            // wave-uniform, 0..39
    if (row < 36) {
      gload_lds16(NFg + (size_t)(bi * 36 + row) * 512 + l * 8, smem + row * 1040);
    } else if (row == 36) {
      gload_lds16(QPg + (size_t)bi * 512 + l * 8, smem + OFF_QP);
    }
  }
  #pragma unroll
  for (int it = 0; it < 2; it++) {
    gload_lds16(W1f + (size_t)(it * 512 + w * 64 + l) * 8,
                smem + OFF_W1 + (it * 512 + w * 64) * 16);
  }

  // ---- per-thread A-gen offsets for the 4 m-tiles ----
  int xoff[4], yoff[4];
  #pragma unroll
  for (int m = 0; m < 4; m++) {
    const int p = mb + wm * 64 + m * 16 + lr;   // <= 767 (ij_tab has 768)
    const int pij = ij_tab[p];
    const int ii = pij / 36;
    const int jj = pij - ii * 36;
    xoff[m] = ii * 1040 + lg * 16;
    yoff[m] = jj * 1040 + lg * 16;
  }
  const int qoff = OFF_QP + lg * 16;
  const int bswz = ((lr >> 1) & 3) << 4;

  asm volatile("s_waitcnt vmcnt(0)" ::: "memory");
  __builtin_amdgcn_s_barrier();

  f32x4 acc[4][8] = {};
  int cur = 0;

  for (int kc = 0; kc < 16; kc++) {
    const int nxt = cur ^ 1;
    if (kc < 15) {                         // async W1(kc+1) -> buf nxt (2 DMA/thread)
      #pragma unroll
      for (int it = 0; it < 2; it++) {
        gload_lds16(W1f + (size_t)(kc + 1) * 8192 + (size_t)(it * 512 + w * 64 + l) * 8,
                    smem + OFF_W1 + nxt * 16384 + (it * 512 + w * 64) * 16);
      }
    }
    {
      const char* w1c = smem + OFF_W1 + cur * 16384;
      const int kb = kc * 64;
      const uint4 qv = *(const uint4*)(smem + qoff + kb);
      half8 bf[8];
      #pragma unroll
      for (int n = 0; n < 8; n++)
        bf[n] = ldh8(w1c + (wn * 128 + n * 16 + lr) * 64 + ((lg * 16) ^ bswz));
      #pragma unroll
      for (int m = 0; m < 4; m++) {
        uint4 x = *(const uint4*)(smem + xoff[m] + kb);
        uint4 y = *(const uint4*)(smem + yoff[m] + kb);
        half8 af = as_h8(pkmul4(pkmul4(x, y), qv));
        #pragma unroll
        for (int n = 0; n < 8; n++)
          acc[m][n] = mfma16h(af, bf[n], acc[m][n]);
      }
    }
    asm volatile("s_waitcnt vmcnt(0)" ::: "memory");
    __builtin_amdgcn_s_barrier();
    cur = nxt;
  }

  // ---- epilogue: two phases of 128 rows; h-tile [128][528B] aliases tables/W1 ----
  half8 w2f[8];
  #pragma unroll
  for (int kk = 0; kk < 8; kk++)
    w2f[kk] = ldh8((const char*)(W2p + lr * 256 + kk * 32 + lg * 8));

  #pragma unroll
  for (int ph = 0; ph < 2; ph++) {
    __syncthreads();                       // prior reads of smem done
    if ((wm >> 1) == ph) {
      #pragma unroll
      for (int m = 0; m < 4; m++) {
        #pragma unroll
        for (int n = 0; n < 8; n++) {
          const int c = wn * 128 + n * 16 + lr;
          const float bv = b1[c];
          #pragma unroll
          for (int qq = 0; qq < 2; qq++) {
            const float v0 = fmaxf(acc[m][n][2 * qq] + bv, 0.f);
            const float v1 = fmaxf(acc[m][n][2 * qq + 1] + bv, 0.f);
            const u32 pk = pkrtz(v0, v1);
            const int r = (wm & 1) * 64 + m * 16 + lg * 4 + 2 * qq;
            *(u16*)(smem + r * 528 + c * 2) = (u16)pk;
            *(u16*)(smem + (r + 1) * 528 + c * 2) = (u16)(pk >> 16);
          }
        }
      }
    }
    __syncthreads();                       // h ready
    {
      f32x4 a2c = {0.f, 0.f, 0.f, 0.f};
      #pragma unroll
      for (int kk = 0; kk < 8; kk++) {
        half8 af = ldh8(smem + (w * 16 + lr) * 528 + kk * 64 + lg * 16);
        a2c = mfma16h(af, w2f[kk], a2c);
      }
      if (lr < 8) {
        const float b2v = b2[lr];
        #pragma unroll
        for (int q = 0; q < 4; q++) {
          const int p = mb + ph * 128 + w * 16 + lg * 4 + q;
          if (p < 630) {                   // pad mask (slots fully written by scatter)
            const int m0 = posPair[(bi * 640 + p) * 2];
            const int m1 = posPair[(bi * 640 + p) * 2 + 1];
            const float val = a2c[q] + b2v;
            out[(size_t)m0 * 8 + lr] = val;
            out[(size_t)m1 * 8 + lr] = val;
          }
        }
      }
    }
  }
}

extern "C" void kernel_launch(void* const* d_in, const int* in_sizes, int n_in,
                              void* d_out, int out_size, void* d_ws, size_t ws_size,
                              hipStream_t stream) {
  const float* node_feats = (const float*)d_in[0];
  const float* q_feats    = (const float*)d_in[1];
  const int*   indexes    = (const int*)d_in[2];
  const float* v_obj = (const float*)d_in[3];
  const float* g_obj = (const float*)d_in[4];
  const float* b_obj = (const float*)d_in[5];
  const float* v_q   = (const float*)d_in[6];
  const float* g_q   = (const float*)d_in[7];
  const float* b_q   = (const float*)d_in[8];
  const float* v_l1  = (const float*)d_in[9];
  const float* g_l1  = (const float*)d_in[10];
  const float* b_l1  = (const float*)d_in[11];
  const float* v_l2  = (const float*)d_in[12];
  const float* g_l2  = (const float*)d_in[13];
  const float* b_l2  = (const float*)d_in[14];
  float* out = (float*)d_out;

  char* ws = (char*)d_ws;
  u16*   node_h  = (u16*)(ws + 0);               // 18,874,368
  u16*   q_h     = (u16*)(ws + 18874368);        //    262,144
  u16*   Wobjh   = (u16*)(ws + 19136512);        //  2,097,152
  u16*   Wqh     = (u16*)(ws + 21233664);        //  1,048,576
  u16*   W1f     = (u16*)(ws + 22282240);        //    262,144 (16x256x32 fp16, swz)
  u16*   W2p     = (u16*)(ws + 22544384);        //      8,192
  u16*   qp_h    = (u16*)(ws + 22552576);        //    131,072 (128x512 fp16)
  u16*   A2h     = (u16*)(ws + 22683648);        //  4,718,592 (nf fp16)
  int*   posPair = (int*)(ws + 27402240);        //    655,360 (128x640x2)
  int*   ij_tab  = (int*)(ws + 28057600);        //      3,072 (768)

  prep<<<dim3(5632), dim3(256), 0, stream>>>(
      node_feats, node_h, q_feats, q_h,
      v_obj, g_obj, v_q, g_q, v_l1, g_l1, v_l2, g_l2,
      Wobjh, Wqh, W1f, W2p, indexes, posPair, ij_tab);

  gemm_n32<<<dim3(37, 16), dim3(256), 0, stream>>>(
      node_h, Wobjh, b_obj, A2h, q_h, Wqh, b_q, qp_h);

  edge_v14<<<dim3(3, 128), dim3(512), EDGE_SMEM, stream>>>(A2h, qp_h, W1f, b_l1,
                                                           W2p, b_l2, posPair, ij_tab, out);
}

// Round 25
// 76.976 us; speedup vs baseline: 1.2086x; 1.2086x over previous
//
#include <hip/hip_runtime.h>
#include <hip/hip_fp16.h>

typedef __attribute__((ext_vector_type(8))) _Float16 half8;
typedef __attribute__((ext_vector_type(2))) __fp16 fp16x2;
typedef __attribute__((ext_vector_type(4))) float f32x4;
typedef unsigned short u16;
typedef unsigned int u32;

__device__ __forceinline__ u16 f2h(float f) {
  union { _Float16 h; u16 u; } cv; cv.h = (_Float16)f; return cv.u;
}

__device__ __forceinline__ u32 pkrtz(float a, float b) {
  union { fp16x2 h; u32 u; } cv;
  cv.h = __builtin_amdgcn_cvt_pkrtz(a, b);
  return cv.u;
}

__device__ __forceinline__ f32x4 mfma16h(half8 a, half8 b, f32x4 c) {
  return __builtin_amdgcn_mfma_f32_16x16x32_f16(a, b, c, 0, 0, 0);
}

__device__ __forceinline__ void gload_lds16(const void* g, void* l) {
  __builtin_amdgcn_global_load_lds(
      (const __attribute__((address_space(1))) void*)g,
      (__attribute__((address_space(3))) void*)l, 16, 0, 0);
}

__device__ __forceinline__ half8 ldh8(const char* p) {
  union { half8 h; int4 v; } r; r.v = *(const int4*)p; return r.h;
}

// 8-wide fp16 product via v_pk_mul_f16
__device__ __forceinline__ uint4 pkmul4(uint4 x, uint4 y) {
  union U { uint4 v; __half2 h[4]; };
  U X, Y, E; X.v = x; Y.v = y;
  #pragma unroll
  for (int i = 0; i < 4; i++) E.h[i] = __hmul2(X.h[i], Y.h[i]);
  return E.v;
}
__device__ __forceinline__ half8 as_h8(uint4 v) {
  union { uint4 v; half8 h; } r; r.v = v; return r.h;
}

// ---- one row of weight-norm (fp16 out), wave-cooperative ----
__device__ __forceinline__ void wn_row(const float* __restrict__ v,
                                       const float* __restrict__ g,
                                       int K, int Nreal, u16* __restrict__ outW,
                                       int row, int l) {
  if (row >= Nreal) {
    for (int k = l; k < K; k += 64) outW[row * K + k] = 0;
    return;
  }
  const float* vr = v + (size_t)row * K;
  float ss = 0.f;
  for (int k = l * 4; k < K; k += 256) {
    f32x4 x = *(const f32x4*)(vr + k);
    ss += x.x * x.x + x.y * x.y + x.z * x.z + x.w * x.w;
  }
  #pragma unroll
  for (int m = 32; m >= 1; m >>= 1) ss += __shfl_xor(ss, m, 64);
  const float scale = g[row] / sqrtf(ss);
  for (int k = l; k < K; k += 64) outW[row * K + k] = f2h(vr[k] * scale);
}

// ================= merged prep (R23-proven): cvt + weight-norm + scatter/ij_tab ====
__global__ __launch_bounds__(256) void prep(
    const float* __restrict__ node, u16* __restrict__ node_h,
    const float* __restrict__ qf, u16* __restrict__ q_h,
    const float* __restrict__ v_obj, const float* __restrict__ g_obj,
    const float* __restrict__ v_q,   const float* __restrict__ g_q,
    const float* __restrict__ v_l1,  const float* __restrict__ g_l1,
    const float* __restrict__ v_l2,  const float* __restrict__ g_l2,
    u16* __restrict__ Wobjh, u16* __restrict__ Wqh,
    u16* __restrict__ W1f,   u16* __restrict__ W2p,
    const int* __restrict__ indexes, int* __restrict__ posPair,
    int* __restrict__ ij_tab) {
  const int b = blockIdx.x;
  if (b < 4672) {
    const int i = (b * 256 + threadIdx.x) * 8;
    const float* in; u16* out; int off;
    if (i < 9437184) { in = node; out = node_h; off = i; }
    else             { in = qf;   out = q_h;    off = i - 9437184; }
    f32x4 a = *(const f32x4*)(in + off);
    f32x4 c = *(const f32x4*)(in + off + 4);
    uint4 r;
    r.x = pkrtz(a.x, a.y); r.y = pkrtz(a.z, a.w);
    r.z = pkrtz(c.x, c.y); r.w = pkrtz(c.z, c.w);
    *(uint4*)(out + off) = r;
    return;
  }
  const int sub = threadIdx.x >> 6, l = threadIdx.x & 63;
  const int b2 = b - 4672;
  if (b2 < 128) {
    wn_row(v_obj, g_obj, 2048, 512, Wobjh, b2 * 4 + sub, l);
  } else if (b2 < 256) {
    wn_row(v_q, g_q, 1024, 512, Wqh, (b2 - 128) * 4 + sub, l);
  } else if (b2 < 320) {
    const int row = (b2 - 256) * 4 + sub;
    const float* vr = v_l1 + (size_t)row * 512;
    float ss = 0.f;
    for (int k = l * 4; k < 512; k += 256) {
      f32x4 x = *(const f32x4*)(vr + k);
      ss += x.x * x.x + x.y * x.y + x.z * x.z + x.w * x.w;
    }
    #pragma unroll
    for (int m = 32; m >= 1; m >>= 1) ss += __shfl_xor(ss, m, 64);
    const float scale = g_l1[row] / sqrtf(ss);
    const int swz = (row >> 1) & 3;
    for (int c = l; c < 512; c += 64) {
      const int kc = c >> 5, col = c & 31, q = col >> 3, e = col & 7;
      W1f[kc * 8192 + row * 32 + ((q ^ swz) << 3) + e] = f2h(vr[c] * scale);
    }
  } else if (b2 < 324) {
    wn_row(v_l2, g_l2, 256, 8, W2p, (b2 - 320) * 4 + sub, l);
  } else {
    const int m = (b2 - 324) * 256 + threadIdx.x;
    if (m < 161280) {
      const int idx = indexes[m];
      const int bi = idx / 1296;
      const int rem = idx - bi * 1296;
      const int i = rem / 36, j = rem - i * 36;
      const int i2 = (i < j) ? i : j, j2 = (i < j) ? j : i;
      const int p = i2 * (71 - i2) / 2 + (j2 - i2 - 1);
      posPair[(bi * 640 + p) * 2 + ((i < j) ? 0 : 1)] = m;
    } else {
      const int u = m - 161280;
      if (u < 1296) {
        const int i = u / 36, j = u - i * 36;
        if (i < j) ij_tab[i * (71 - i) / 2 + (j - i - 1)] = u;
      } else if (u < 1306) {
        ij_tab[630 + (u - 1296)] = 35 * 36 + 35;
      }
    }
  }
}

// ================= stage-1 GEMM, 128x32 N-tiles (R21-proven) =================
__global__ __launch_bounds__(256, 3) void gemm_n32(
    const u16* __restrict__ node_h, const u16* __restrict__ Wobjh,
    const float* __restrict__ b_obj, u16* __restrict__ A2h,
    const u16* __restrict__ q_h, const u16* __restrict__ Wqh,
    const float* __restrict__ b_q, u16* __restrict__ qp_h) {
  __shared__ char smem[2][20480];   // [buf][ A 128x128B | B 32x128B ]
  const int t = threadIdx.x, l = t & 63, w = t >> 6;
  const int lr = l & 15, lg = l >> 4;
  const int wm = w & 1, wn2 = w >> 1;

  const bool isq = (blockIdx.x == 36);
  const u16* Ab = isq ? q_h : node_h;
  const u16* Wb = isq ? Wqh : Wobjh;
  const float* bias = isq ? b_q : b_obj;
  u16* outp = isq ? qp_h : A2h;
  const int K = isq ? 1024 : 2048;
  const int nstep = isq ? 16 : 32;
  const int bm = isq ? 0 : blockIdx.x * 128;
  const int bn = blockIdx.y * 32;
  const int ldb = K * 2;

  const char* Abase = (const char*)(Ab + (size_t)bm * K);
  const char* Bbase = (const char*)(Wb + (size_t)bn * K);

  auto stage = [&](int buf, int ks) {
    const char* asrc = Abase + ks * 128;
    const char* bsrc = Bbase + ks * 128;
    #pragma unroll
    for (int it = 0; it < 4; it++) {
      const int c = it * 256 + w * 64 + l;
      const int row = c >> 3;
      const int cb = ((c & 7) * 16) ^ ((row & 7) << 4);
      gload_lds16(asrc + (size_t)row * ldb + cb, &smem[buf][(it * 256 + w * 64) * 16]);
    }
    {
      const int c = w * 64 + l;
      const int row = c >> 3;
      const int cb = ((c & 7) * 16) ^ ((row & 7) << 4);
      gload_lds16(bsrc + (size_t)row * ldb + cb,
                  &smem[buf][16384 + (w * 64) * 16]);
    }
  };

  stage(0, 0);
  asm volatile("s_waitcnt vmcnt(0)" ::: "memory");
  __builtin_amdgcn_s_barrier();

  f32x4 acc[4] = {};
  f32x4 acc2[4] = {};
  for (int ks = 0; ks < nstep; ks++) {
    const int cur = ks & 1;
    if (ks + 1 < nstep) stage(cur ^ 1, ks + 1);
    const char* As = smem[cur];
    const char* Bs = smem[cur] + 16384;
    #pragma unroll
    for (int kk = 0; kk < 2; kk++) {
      const int kswz = (kk * 64 + lg * 16) ^ ((lr & 7) << 4);
      half8 af[4], bf;
      #pragma unroll
      for (int m = 0; m < 4; m++)
        af[m] = ldh8(As + (wm * 64 + m * 16 + lr) * 128 + kswz);
      bf = ldh8(Bs + (wn2 * 16 + lr) * 128 + kswz);
      acc[0] = mfma16h(af[0], bf, acc[0]);
      acc[1] = mfma16h(af[1], bf, acc[1]);
      acc2[0] = mfma16h(af[2], bf, acc2[0]);
      acc2[1] = mfma16h(af[3], bf, acc2[1]);
    }
    asm volatile("s_waitcnt vmcnt(0)" ::: "memory");
    __builtin_amdgcn_s_barrier();
  }

  const int c = bn + wn2 * 16 + lr;
  const float bv = bias[c];
  #pragma unroll
  for (int m = 0; m < 4; m++) {
    const f32x4 a = (m < 2) ? acc[m] : acc2[m - 2];
    #pragma unroll
    for (int q = 0; q < 4; q++) {
      const int r = bm + wm * 64 + m * 16 + lg * 4 + q;
      outp[(size_t)r * 512 + c] = f2h(a[q] + bv);
    }
  }
}

// ================= fused edge kernel v15: M=160, grid (4,128)=512 = 2.0 blocks/CU ====
// v11 inner loop preserved (same swizzles, same per-tile work); M-tiles 4 -> 5
// (acc[5][8], wave tile 80x128). 630 real pairs -> 640 rows (pad 10, same as
// v11) with ZERO scheduling tail. Epilogue: two 80-row phases ([80][528B] =
// 42.2 KB aliases tables/W1). LDS 71,232 B -> 2 blocks/CU.
#define OFF_QP 37440
#define OFF_W1 38464
#define EDGE_SMEM 71232

__global__ __launch_bounds__(256, 2) void edge_v15(
    const u16* __restrict__ NFg, const u16* __restrict__ QPg,
    const u16* __restrict__ W1f, const float* __restrict__ b1,
    const u16* __restrict__ W2p, const float* __restrict__ b2,
    const int* __restrict__ posPair, const int* __restrict__ ij_tab,
    float* __restrict__ out) {
  extern __shared__ char smem[];
  const int t = threadIdx.x, l = t & 63, w = t >> 6;
  const int lr = l & 15, lg = l >> 4;
  const int wm = w & 1, wn = w >> 1;
  const int bi = blockIdx.y;
  const int mb = blockIdx.x * 160;

  #pragma unroll
  for (int it = 0; it < 10; it++) {
    const int row = it * 4 + w;
    if (row < 36) {
      gload_lds16(NFg + (size_t)(bi * 36 + row) * 512 + l * 8, smem + row * 1040);
    } else if (row == 36) {
      gload_lds16(QPg + (size_t)bi * 512 + l * 8, smem + OFF_QP);
    }
  }
  #pragma unroll
  for (int it = 0; it < 4; it++) {
    gload_lds16(W1f + (size_t)(it * 256 + w * 64 + l) * 8,
                smem + OFF_W1 + (it * 256 + w * 64) * 16);
  }

  int xoff[5], yoff[5];
  #pragma unroll
  for (int m = 0; m < 5; m++) {
    const int p = mb + wm * 80 + m * 16 + lr;   // <= 639
    const int pij = ij_tab[p];
    const int ii = pij / 36;
    const int jj = pij - ii * 36;
    xoff[m] = ii * 1040 + lg * 16;
    yoff[m] = jj * 1040 + lg * 16;
  }
  const int qoff = OFF_QP + lg * 16;
  const int bswz = ((lr >> 1) & 3) << 4;

  asm volatile("s_waitcnt vmcnt(0)" ::: "memory");
  __builtin_amdgcn_s_barrier();

  f32x4 acc[5][8] = {};
  int cur = 0;

  for (int kc = 0; kc < 16; kc++) {
    const int nxt = cur ^ 1;
    if (kc < 15) {
      #pragma unroll
      for (int it = 0; it < 4; it++) {
        gload_lds16(W1f + (size_t)(kc + 1) * 8192 + (size_t)(it * 256 + w * 64 + l) * 8,
                    smem + OFF_W1 + nxt * 16384 + (it * 256 + w * 64) * 16);
      }
    }
    {
      const char* w1c = smem + OFF_W1 + cur * 16384;
      const int kb = kc * 64;
      const uint4 qv = *(const uint4*)(smem + qoff + kb);
      half8 bf[8];
      #pragma unroll
      for (int n = 0; n < 8; n++)
        bf[n] = ldh8(w1c + (wn * 128 + n * 16 + lr) * 64 + ((lg * 16) ^ bswz));
      #pragma unroll
      for (int m = 0; m < 5; m++) {
        uint4 x = *(const uint4*)(smem + xoff[m] + kb);
        uint4 y = *(const uint4*)(smem + yoff[m] + kb);
        half8 af = as_h8(pkmul4(pkmul4(x, y), qv));
        #pragma unroll
        for (int n = 0; n < 8; n++)
          acc[m][n] = mfma16h(af, bf[n], acc[m][n]);
      }
    }
    asm volatile("s_waitcnt vmcnt(0)" ::: "memory");
    __builtin_amdgcn_s_barrier();
    cur = nxt;
  }

  // ---- epilogue: two phases of 80 rows; h-tile [80][528B] aliases tables/W1 ----
  half8 w2f[8];
  #pragma unroll
  for (int kk = 0; kk < 8; kk++)
    w2f[kk] = ldh8((const char*)(W2p + lr * 256 + kk * 32 + lg * 8));

  #pragma unroll
  for (int ph = 0; ph < 2; ph++) {
    __syncthreads();                       // prior smem reads done
    if (wm == ph) {
      #pragma unroll
      for (int m = 0; m < 5; m++) {
        #pragma unroll
        for (int n = 0; n < 8; n++) {
          const int c = wn * 128 + n * 16 + lr;
          const float bv = b1[c];
          #pragma unroll
          for (int qq = 0; qq < 2; qq++) {
            const float v0 = fmaxf(acc[m][n][2 * qq] + bv, 0.f);
            const float v1 = fmaxf(acc[m][n][2 * qq + 1] + bv, 0.f);
            const u32 pk = pkrtz(v0, v1);
            const int r = m * 16 + lg * 4 + 2 * qq;
            *(u16*)(smem + r * 528 + c * 2) = (u16)pk;
            *(u16*)(smem + (r + 1) * 528 + c * 2) = (u16)(pk >> 16);
          }
        }
      }
    }
    __syncthreads();                       // h ready
    #pragma unroll
    for (int tt = 0; tt < 2; tt++) {
      const int tile = tt * 4 + w;
      if (tile < 5) {
        f32x4 a2c = {0.f, 0.f, 0.f, 0.f};
        #pragma unroll
        for (int kk = 0; kk < 8; kk++) {
          half8 af = ldh8(smem + (tile * 16 + lr) * 528 + kk * 64 + lg * 16);
          a2c = mfma16h(af, w2f[kk], a2c);
        }
        if (lr < 8) {
          const float b2v = b2[lr];
          #pragma unroll
          for (int q = 0; q < 4; q++) {
            const int p = mb + ph * 80 + tile * 16 + lg * 4 + q;
            if (p < 630) {
              const int m0 = posPair[(bi * 640 + p) * 2];
              const int m1 = posPair[(bi * 640 + p) * 2 + 1];
              const float val = a2c[q] + b2v;
              out[(size_t)m0 * 8 + lr] = val;
              out[(size_t)m1 * 8 + lr] = val;
            }
          }
        }
      }
    }
  }
}

extern "C" void kernel_launch(void* const* d_in, const int* in_sizes, int n_in,
                              void* d_out, int out_size, void* d_ws, size_t ws_size,
                              hipStream_t stream) {
  const float* node_feats = (const float*)d_in[0];
  const float* q_feats    = (const float*)d_in[1];
  const int*   indexes    = (const int*)d_in[2];
  const float* v_obj = (const float*)d_in[3];
  const float* g_obj = (const float*)d_in[4];
  const float* b_obj = (const float*)d_in[5];
  const float* v_q   = (const float*)d_in[6];
  const float* g_q   = (const float*)d_in[7];
  const float* b_q   = (const float*)d_in[8];
  const float* v_l1  = (const float*)d_in[9];
  const float* g_l1  = (const float*)d_in[10];
  const float* b_l1  = (const float*)d_in[11];
  const float* v_l2  = (const float*)d_in[12];
  const float* g_l2  = (const float*)d_in[13];
  const float* b_l2  = (const float*)d_in[14];
  float* out = (float*)d_out;

  char* ws = (char*)d_ws;
  u16*   node_h  = (u16*)(ws + 0);               // 18,874,368
  u16*   q_h     = (u16*)(ws + 18874368);        //    262,144
  u16*   Wobjh   = (u16*)(ws + 19136512);        //  2,097,152
  u16*   Wqh     = (u16*)(ws + 21233664);        //  1,048,576
  u16*   W1f     = (u16*)(ws + 22282240);        //    262,144 (16x256x32 fp16, swz)
  u16*   W2p     = (u16*)(ws + 22544384);        //      8,192
  u16*   qp_h    = (u16*)(ws + 22552576);        //    131,072 (128x512 fp16)
  u16*   A2h     = (u16*)(ws + 22683648);        //  4,718,592 (nf fp16)
  int*   posPair = (int*)(ws + 27402240);        //    655,360 (128x640x2)
  int*   ij_tab  = (int*)(ws + 28057600);        //      2,560 (640)

  prep<<<dim3(5632), dim3(256), 0, stream>>>(
      node_feats, node_h, q_feats, q_h,
      v_obj, g_obj, v_q, g_q, v_l1, g_l1, v_l2, g_l2,
      Wobjh, Wqh, W1f, W2p, indexes, posPair, ij_tab);

  gemm_n32<<<dim3(37, 16), dim3(256), 0, stream>>>(
      node_h, Wobjh, b_obj, A2h, q_h, Wqh, b_q, qp_h);

  edge_v15<<<dim3(4, 128), dim3(256), EDGE_SMEM, stream>>>(A2h, qp_h, W1f, b_l1,
                                                           W2p, b_l2, posPair, ij_tab, out);
}